// Round 7
// baseline (849.854 us; speedup 1.0000x reference)
//
#include <hip/hip_runtime.h>

// Segmenter forward: clustering (logits/argmax/EMA centers) + neuralef loss.
// Round 7: k_cacc (O(N*NC) serial scan, 195us latency-bound) replaced by
// counting sort: argmax+count -> prefix -> scatter -> per-cluster coalesced
// accumulate fused with EMA center write. buildA/gpsiM unchanged.

#define NPTS 8192
#define DM   768
#define DP   512
#define NC   128
#define SCALE 0.001220703125f   // 10/8192, exact
#define ALPHAC 0.02f

// ---- ws offsets in float elements ----
#define O_PSIN   0ul            // 8192*512 fp32 (reused as g2 after clustering)
#define O_GPSI0  4194304ul      // 8192*512 fp32 (kz=0 partial)
#define O_GPSI1  8388608ul      // 8192*512 fp32 (kz=1 partial)
#define O_FFH    12582912ul     // 8192*768 bf16 (region reused as g3 after buildA)
#define O_YTH    18874368ul     // 512*8192 bf16 (transposed, scaled)
#define O_ROWSUM 23068672ul     // 8192
#define O_DRS    23076864ul     // 8192
#define O_TC     23085056ul     // 128
#define O_CNT    23085184ul     // 128 (int)
#define O_ORDER  23085312ul     // 8192 (int, cluster-sorted row ids)
#define O_OFFS   23093504ul     // 128 (int)
#define O_OFFSW  23093632ul     // 128 (int)
#define O_ASSIGN 23150848ul     // 8192 int
#define O_R      23159040ul     // 512*512
#define O_SNORM  23421184ul     // 8192
#define O_AHI    23429376ul     // 8192*8192 bf16 (single plane)
#define WS_END   56983808ul     // ~228 MB

// output offsets (floats)
#define OUT_LOGITS  0ul
#define OUT_CENTERS 1048576ul
#define OUT_SCAL    1114112ul

typedef short  short8 __attribute__((ext_vector_type(8)));
typedef float  f32x4  __attribute__((ext_vector_type(4)));

__device__ __forceinline__ float wave_reduce_sum(float v) {
#pragma unroll
  for (int m = 1; m < 64; m <<= 1) v += __shfl_xor(v, m, 64);
  return v;
}

__device__ __forceinline__ unsigned short f2bf(float x) {
  unsigned int u = __float_as_uint(x);
  unsigned int r = (u + 0x7fffu + ((u >> 16) & 1u)) >> 16;  // RNE
  return (unsigned short)r;
}
__device__ __forceinline__ float bf2f(unsigned short b) {
  return __uint_as_float((unsigned int)b << 16);
}

// async global->LDS 16B: HW writes wave-uniform base + lane*16
__device__ __forceinline__ void stage16(ushort* lds_wave_base, ushort* lds_exact,
                                        const ushort* g) {
#if __has_builtin(__builtin_amdgcn_global_load_lds)
  __builtin_amdgcn_global_load_lds(
      (const __attribute__((address_space(1))) unsigned int*)g,
      (__attribute__((address_space(3))) unsigned int*)lds_wave_base, 16, 0, 0);
#else
  *(uint4*)lds_exact = *(const uint4*)g;
#endif
}

// LDS plane layout: [ROWS][32 bf16], chunk slot s of row holds global k-chunk
// s ^ ((row>>1)&3): 16-lane frag reads map to 8 distinct bank-quads (2-way, free)
__device__ __forceinline__ short8 read_frag(const ushort* plane, int row, int x) {
  int kc = x ^ ((row >> 1) & 3);
  return *(const short8*)(plane + row * 32 + kc * 8);
}

// stage one [ROWS][32] plane from global (row0.., k0..k0+32) with pre-swizzled src
template <int ROWS>
__device__ __forceinline__ void stage_plane(ushort* ldsP, const ushort* __restrict__ src,
                                            int stride, int row0, int k0, int tid) {
  constexpr int NIT = ROWS * 4 / 256;
#pragma unroll
  for (int j = 0; j < NIT; ++j) {
    int c = j * 256 + tid;
    int row = c >> 2;
    int kc = (c & 3) ^ ((row >> 1) & 3);
    stage16(ldsP + (size_t)(c & ~63) * 8, ldsP + (size_t)c * 8,
            src + (size_t)(row0 + row) * stride + k0 + kc * 8);
  }
}

// ================= templated MFMA GEMM core (single bf16 plane per side) =====
template <int BM, int BN>
__device__ void gemm_core(const ushort* __restrict__ aH, const ushort* __restrict__ bH,
                          int strideA, int strideB, int rowA0, int rowB0,
                          int kBase, int kLen, ushort* lds, f32x4 (&acc)[4][BN / 32]) {
  constexpr int NF = BN / 32;
  constexpr int OFF_AH = 0;
  constexpr int OFF_BH = BM * 32;

  const int tid = threadIdx.x;
  const int lane = tid & 63;
  const int l15 = lane & 15;
  const int x16 = lane >> 4;
  const int wid = tid >> 6, wr = wid >> 1, wc = wid & 1;
  const int arow = wr * 64;
  const int bcol = wc * (BN / 2);

  for (int ks = 0; ks < kLen; ks += 32) {
    const int k0 = kBase + ks;
    stage_plane<BM>(lds + OFF_AH, aH, strideA, rowA0, k0, tid);
    stage_plane<BN>(lds + OFF_BH, bH, strideB, rowB0, k0, tid);
    __syncthreads();
    short8 ah[4];
#pragma unroll
    for (int m = 0; m < 4; ++m)
      ah[m] = read_frag(lds + OFF_AH, arow + m * 16 + l15, x16);
#pragma unroll
    for (int n = 0; n < NF; ++n) {
      short8 bh = read_frag(lds + OFF_BH, bcol + n * 16 + l15, x16);
#pragma unroll
      for (int m = 0; m < 4; ++m)
        acc[m][n] = __builtin_amdgcn_mfma_f32_16x16x32_bf16(ah[m], bh, acc[m][n], 0, 0, 0);
    }
    __syncthreads();
  }
}

// ---------- K1a: L2 normalize FF rows -> bf16 hi plane ----------
__global__ __launch_bounds__(256) void k_l2norm_ff(const float* __restrict__ in,
                                                   ushort* __restrict__ oh) {
  int row = blockIdx.x;
  const float* r = in + (size_t)row * DM;
  float v[3];
  float ss = 0.f;
#pragma unroll
  for (int s = 0; s < 3; ++s) { v[s] = r[threadIdx.x + s * 256]; ss += v[s] * v[s]; }
  ss = wave_reduce_sum(ss);
  __shared__ float w[4];
  if ((threadIdx.x & 63) == 0) w[threadIdx.x >> 6] = ss;
  __syncthreads();
  float inv = 1.0f / fmaxf(sqrtf(w[0] + w[1] + w[2] + w[3]), 1e-12f);
#pragma unroll
  for (int s = 0; s < 3; ++s)
    oh[(size_t)row * DM + threadIdx.x + s * 256] = f2bf(v[s] * inv);
}

// ---------- K1b: L2 normalize Psi rows -> fp32 (+ snorm = sum(psin^2)) ----------
__global__ __launch_bounds__(256) void k_l2norm_f32(const float* __restrict__ in,
                                                    float* __restrict__ out,
                                                    float* __restrict__ snorm) {
  int row = blockIdx.x;
  const float* r = in + (size_t)row * DP;
  float v[2];
  float ss = 0.f;
#pragma unroll
  for (int s = 0; s < 2; ++s) { v[s] = r[threadIdx.x + s * 256]; ss += v[s] * v[s]; }
  ss = wave_reduce_sum(ss);
  __shared__ float w[4];
  if ((threadIdx.x & 63) == 0) w[threadIdx.x >> 6] = ss;
  __syncthreads();
  float tot = w[0] + w[1] + w[2] + w[3];
  float inv = 1.0f / fmaxf(sqrtf(tot), 1e-12f);
#pragma unroll
  for (int s = 0; s < 2; ++s)
    out[(size_t)row * DP + threadIdx.x + s * 256] = v[s] * inv;
  if (threadIdx.x == 0) snorm[row] = tot * inv * inv;
}

// ---------- K2: cluster-center squared norms ----------
__global__ __launch_bounds__(256) void k_cnorm(const float* __restrict__ cc,
                                               float* __restrict__ tc) {
  int c = blockIdx.x;
  float x0 = cc[(size_t)c * DP + threadIdx.x];
  float x1 = cc[(size_t)c * DP + threadIdx.x + 256];
  float ss = wave_reduce_sum(x0 * x0 + x1 * x1);
  __shared__ float w[4];
  if ((threadIdx.x & 63) == 0) w[threadIdx.x >> 6] = ss;
  __syncthreads();
  if (threadIdx.x == 0) tc[c] = w[0] + w[1] + w[2] + w[3];
}

// ---------- K3a: logits = 2*psin@cc^T - snorm_i - tc_j  (fp32 tile GEMM) ----------
__global__ __launch_bounds__(256) void k_logitsG(const float* __restrict__ psin,
                                                 const float* __restrict__ cc,
                                                 const float* __restrict__ tc,
                                                 const float* __restrict__ snorm,
                                                 float* __restrict__ out_logits) {
  __shared__ float Ps[64][32];    // [k][row]
  __shared__ float Cs[64][128];   // [k][col]
  const int r0 = blockIdx.x * 32;
  const int tid = threadIdx.x;
  const int tx = tid & 31, ty = tid >> 5;   // cols tx*4.., rows ty*4..
  float acc[4][4] = {};

  for (int k0 = 0; k0 < DP; k0 += 64) {
#pragma unroll
    for (int j = 0; j < 2; ++j) {
      int idx = tid * 2 + j;
      int row = idx >> 4, q = idx & 15;
      float4 v = *(const float4*)(psin + (size_t)(r0 + row) * DP + k0 + q * 4);
      Ps[q * 4 + 0][row] = v.x; Ps[q * 4 + 1][row] = v.y;
      Ps[q * 4 + 2][row] = v.z; Ps[q * 4 + 3][row] = v.w;
    }
#pragma unroll
    for (int j = 0; j < 8; ++j) {
      int idx = tid * 8 + j;
      int c = idx >> 4, q = idx & 15;
      float4 v = *(const float4*)(cc + (size_t)c * DP + k0 + q * 4);
      Cs[q * 4 + 0][c] = v.x; Cs[q * 4 + 1][c] = v.y;
      Cs[q * 4 + 2][c] = v.z; Cs[q * 4 + 3][c] = v.w;
    }
    __syncthreads();
#pragma unroll 8
    for (int k = 0; k < 64; ++k) {
      float a4[4], b4[4];
      *(float4*)a4 = *(const float4*)&Ps[k][ty * 4];
      *(float4*)b4 = *(const float4*)&Cs[k][tx * 4];
#pragma unroll
      for (int u = 0; u < 4; ++u)
#pragma unroll
        for (int v = 0; v < 4; ++v) acc[u][v] = fmaf(a4[u], b4[v], acc[u][v]);
    }
    __syncthreads();
  }

  float4 tcv = *(const float4*)(tc + tx * 4);
#pragma unroll
  for (int u = 0; u < 4; ++u) {
    int row = r0 + ty * 4 + u;
    float sn = snorm[row];
    float4 o;
    o.x = 2.0f * acc[u][0] - sn - tcv.x;
    o.y = 2.0f * acc[u][1] - sn - tcv.y;
    o.z = 2.0f * acc[u][2] - sn - tcv.z;
    o.w = 2.0f * acc[u][3] - sn - tcv.w;
    *(float4*)(out_logits + (size_t)row * NC + tx * 4) = o;
  }
}

// ---------- K3b: argmax per row + cluster counts ----------
__global__ __launch_bounds__(256) void k_argmax(const float* __restrict__ logits,
                                                int* __restrict__ assign,
                                                int* __restrict__ cnt) {
  int row = blockIdx.x * 4 + (threadIdx.x >> 6);
  int lane = threadIdx.x & 63;
  const float* lr = logits + (size_t)row * NC;
  float v0 = lr[lane], v1 = lr[lane + 64];
  float bv; int bi;
  if (v1 > v0) { bv = v1; bi = lane + 64; } else { bv = v0; bi = lane; }
#pragma unroll
  for (int m = 1; m < 64; m <<= 1) {
    float ov = __shfl_xor(bv, m);
    int oi = __shfl_xor(bi, m);
    if (ov > bv || (ov == bv && oi < bi)) { bv = ov; bi = oi; }
  }
  if (lane == 0) {
    assign[row] = bi;
    atomicAdd(&cnt[bi], 1);
  }
}

// ---------- K4a: exclusive prefix of cluster counts ----------
__global__ __launch_bounds__(NC) void k_prefix(const int* __restrict__ cnt,
                                               int* __restrict__ offs,
                                               int* __restrict__ offsw) {
  __shared__ int s[NC];
  int t = threadIdx.x;
  int v0 = cnt[t];
  s[t] = v0;
  __syncthreads();
  for (int off = 1; off < NC; off <<= 1) {
    int v = (t >= off) ? s[t - off] : 0;
    __syncthreads();
    s[t] += v;
    __syncthreads();
  }
  int excl = s[t] - v0;
  offs[t] = excl;
  offsw[t] = excl;
}

// ---------- K4b: scatter row ids into cluster-sorted order ----------
__global__ __launch_bounds__(256) void k_scatter(const int* __restrict__ assign,
                                                 int* __restrict__ offsw,
                                                 int* __restrict__ order) {
  int i = blockIdx.x * 256 + threadIdx.x;
  int c = assign[i];
  int pos = atomicAdd(&offsw[c], 1);
  order[pos] = i;
}

// ---------- K4c: per-cluster sum of psin members + EMA center write ----------
__global__ __launch_bounds__(256) void k_csum(const int* __restrict__ offs,
                                              const int* __restrict__ cnt,
                                              const int* __restrict__ order,
                                              const float* __restrict__ psin,
                                              const float* __restrict__ cc,
                                              float* __restrict__ out_centers) {
  int c = blockIdx.x;
  int tid = threadIdx.x;
  int start = offs[c], n = cnt[c];
  __shared__ int sa[256];
  float a0 = 0.f, a1 = 0.f;
  for (int base = 0; base < n; base += 256) {
    int m = min(n - base, 256);
    if (tid < m) sa[tid] = order[start + base + tid];
    __syncthreads();
    for (int j = 0; j < m; ++j) {
      const float* pr = psin + (size_t)sa[j] * DP;
      a0 += pr[tid];
      a1 += pr[tid + 256];
    }
    __syncthreads();
  }
  float denom = fmaxf((float)n, 1.0f);
  size_t o = (size_t)c * DP + tid;
  out_centers[o]       = cc[o]       * 0.9f + (a0 / denom) * 0.1f;
  out_centers[o + 256] = cc[o + 256] * 0.9f + (a1 / denom) * 0.1f;
}

// ---------- K6: buildA symmetric (upper-tri blocks, mirror via LDS transpose) ----------
__global__ __launch_bounds__(256) void k_buildA(const ushort* __restrict__ ffh,
                                                ushort* __restrict__ Ah,
                                                float* __restrict__ rowsum) {
  __shared__ ushort lds[16384];
  // XCD-bijective swizzle: 2080 = 8 * 260 exact
  int sid = (blockIdx.x & 7) * 260 + (blockIdx.x >> 3);
  int rem = sid;
  int bi = 0;
  while (rem >= 64 - bi) { rem -= 64 - bi; ++bi; }
  int bj = bi + rem;

  f32x4 acc[4][4];
#pragma unroll
  for (int m = 0; m < 4; ++m)
#pragma unroll
    for (int n = 0; n < 4; ++n) acc[m][n] = (f32x4)0.0f;

  gemm_core<128, 128>(ffh, ffh, DM, DM, bi * 128, bj * 128, 0, DM, lds, acc);

  const int tid = threadIdx.x;
  const int lane = tid & 63, l15 = lane & 15;
  const int wid = tid >> 6, wr = wid >> 1, wc = wid & 1;
  const int rbase = bi * 128 + wr * 64;
  const int cbase = bj * 128 + wc * 64;

#pragma unroll
  for (int m = 0; m < 4; ++m) {
#pragma unroll
    for (int r = 0; r < 4; ++r) {
      int grow = rbase + m * 16 + (lane >> 4) * 4 + r;
      float rsv = 0.f;
#pragma unroll
      for (int n = 0; n < 4; ++n) {
        int gcol = cbase + n * 16 + l15;
        float v = fmaxf(acc[m][n][r], 0.f);
        if (grow == gcol) v = 0.f;
        rsv += v;
        Ah[(size_t)grow * NPTS + gcol] = f2bf(v);
      }
      rsv += __shfl_xor(rsv, 1); rsv += __shfl_xor(rsv, 2);
      rsv += __shfl_xor(rsv, 4); rsv += __shfl_xor(rsv, 8);
      if (l15 == 0) atomicAdd(&rowsum[grow], rsv);
    }
  }

  if (bi != bj) {
    __syncthreads();
#pragma unroll
    for (int m = 0; m < 4; ++m) {
#pragma unroll
      for (int n = 0; n < 4; ++n) {
        int lc = wc * 64 + n * 16 + l15;
        int swz = lc & 7;
#pragma unroll
        for (int r = 0; r < 4; ++r) {
          int lr = wr * 64 + m * 16 + (lane >> 4) * 4 + r;
          float v = fmaxf(acc[m][n][r], 0.f);
          lds[lc * 128 + ((((lr >> 3) ^ swz)) << 3) + (lr & 7)] = f2bf(v);
        }
      }
    }
#pragma unroll
    for (int n = 0; n < 4; ++n) {
      float cs = 0.f;
#pragma unroll
      for (int m = 0; m < 4; ++m)
#pragma unroll
        for (int r = 0; r < 4; ++r) cs += fmaxf(acc[m][n][r], 0.f);
      cs += __shfl_xor(cs, 16); cs += __shfl_xor(cs, 32);
      if (lane < 16) atomicAdd(&rowsum[cbase + n * 16 + l15], cs);
    }
    __syncthreads();
    int lc = tid >> 1;
    int cg = (tid & 1) * 8;
    int swz = lc & 7;
    size_t gbase = (size_t)(bj * 128 + lc) * NPTS + bi * 128;
#pragma unroll
    for (int j = 0; j < 8; ++j) {
      int ch = cg + j;
      short8 vv = *(const short8*)&lds[lc * 128 + ((ch ^ swz) << 3)];
      *(short8*)(Ah + gbase + ch * 8) = vv;
    }
  }
}

// ---------- K7: Drs ----------
__global__ __launch_bounds__(256) void k_drs(const float* __restrict__ rowsum,
                                             float* __restrict__ drs) {
  int i = blockIdx.x * 256 + threadIdx.x;
  drs[i] = 1.0f / sqrtf(rowsum[i] * (1.0f / 8191.0f));
}

// ---------- K8: Yt = bf16((SCALE * Drs_k) * Psi)^T  [512][8192] ----------
__global__ __launch_bounds__(256) void k_ytrans(const float* __restrict__ psi,
                                                const float* __restrict__ drs,
                                                ushort* __restrict__ Yh) {
  __shared__ float sm[64][65];
  int k0 = blockIdx.x * 64, d0 = blockIdx.y * 64;
  int tid = threadIdx.x;
  int rr = tid >> 4, c4 = (tid & 15) * 4;
#pragma unroll
  for (int s = 0; s < 4; ++s) {
    int kk = s * 16 + rr;
    float sd = drs[k0 + kk] * SCALE;
    float4 v = *(const float4*)(psi + (size_t)(k0 + kk) * DP + d0 + c4);
    sm[kk][c4 + 0] = v.x * sd; sm[kk][c4 + 1] = v.y * sd;
    sm[kk][c4 + 2] = v.z * sd; sm[kk][c4 + 3] = v.w * sd;
  }
  __syncthreads();
  int d = tid >> 2, kq = (tid & 3) * 16;
  short8 h0, h1;
#pragma unroll
  for (int t = 0; t < 8; ++t) {
    h0[t] = (short)f2bf(sm[kq + t][d]);
    h1[t] = (short)f2bf(sm[kq + 8 + t][d]);
  }
  size_t off = (size_t)(d0 + d) * NPTS + k0 + kq;
  *(short8*)(Yh + off) = h0; *(short8*)(Yh + off + 8) = h1;
}

// ---------- K9: gPsi partial = A_h @ Yt^T (XCD-swizzled 1-D grid of 512) ----------
__global__ __launch_bounds__(256) void k_gpsiM(const ushort* __restrict__ Ah,
                                               const ushort* __restrict__ Yh,
                                               float* __restrict__ g0,
                                               float* __restrict__ g1,
                                               float* __restrict__ g2,
                                               float* __restrict__ g3) {
  __shared__ ushort lds[12288];
  int sw = (blockIdx.x & 7) * 64 + (blockIdx.x >> 3);
  int nb = sw & 1, ib = (sw >> 1) & 63, kz = sw >> 7;
  float* gout = (kz == 0) ? g0 : (kz == 1) ? g1 : (kz == 2) ? g2 : g3;
  f32x4 acc[4][8];
#pragma unroll
  for (int m = 0; m < 4; ++m)
#pragma unroll
    for (int n = 0; n < 8; ++n) acc[m][n] = (f32x4)0.0f;

  gemm_core<128, 256>(Ah, Yh, NPTS, NPTS, ib * 128, nb * 256, kz * 2048, 2048,
                      lds, acc);

  int lane = threadIdx.x & 63, l15 = lane & 15;
  int wid = threadIdx.x >> 6, wr = wid >> 1, wc = wid & 1;
  int rbase = ib * 128 + wr * 64;
  int cbase = nb * 256 + wc * 128;
#pragma unroll
  for (int m = 0; m < 4; ++m) {
#pragma unroll
    for (int r = 0; r < 4; ++r) {
      int grow = rbase + m * 16 + (lane >> 4) * 4 + r;
#pragma unroll
      for (int n = 0; n < 8; ++n) {
        int gcol = cbase + n * 16 + l15;
        gout[(size_t)grow * DP + gcol] = acc[m][n][r];
      }
    }
  }
}

// ---------- K10: R = Psi_l^T @ (Drs_i * (g0+g1+g2+g3)) ----------
__global__ __launch_bounds__(256) void k_R(const float* __restrict__ psi,
                                           const float* __restrict__ g0,
                                           const float* __restrict__ g1,
                                           const float* __restrict__ g2,
                                           const float* __restrict__ g3,
                                           const float* __restrict__ drs,
                                           float* __restrict__ R) {
  int t = blockIdx.x;
  int tp = t & 7, tq = t >> 3;
  int ks = blockIdx.y;
  int tid = threadIdx.x;
  int tx = tid & 15, ty = tid >> 4;
  __shared__ float Ps[32][64];
  __shared__ float Gs[32][64];
  float acc[4][4] = {};

  for (int k0 = ks * 1024; k0 < ks * 1024 + 1024; k0 += 32) {
#pragma unroll
    for (int s = 0; s < 2; ++s) {
      int idx = tid + s * 256;
      int kk = idx >> 4, pq = idx & 15;
      float4 p = *(const float4*)(psi + (size_t)(k0 + kk) * DP + tp * 64 + pq * 4);
      p.x *= SCALE; p.y *= SCALE; p.z *= SCALE; p.w *= SCALE;
      *(float4*)&Ps[kk][pq * 4] = p;
      float dk = drs[k0 + kk];
      size_t goff = (size_t)(k0 + kk) * DP + tq * 64 + pq * 4;
      float4 ga = *(const float4*)(g0 + goff);
      float4 gb = *(const float4*)(g1 + goff);
      float4 gc = *(const float4*)(g2 + goff);
      float4 gd = *(const float4*)(g3 + goff);
      ga.x = (ga.x + gb.x + gc.x + gd.x) * dk;
      ga.y = (ga.y + gb.y + gc.y + gd.y) * dk;
      ga.z = (ga.z + gb.z + gc.z + gd.z) * dk;
      ga.w = (ga.w + gb.w + gc.w + gd.w) * dk;
      *(float4*)&Gs[kk][pq * 4] = ga;
    }
    __syncthreads();
#pragma unroll 8
    for (int k = 0; k < 32; ++k) {
      float av[4], bvv[4];
      *(float4*)&av[0] = *(const float4*)&Ps[k][ty * 4];
      *(float4*)&bvv[0] = *(const float4*)&Gs[k][tx * 4];
#pragma unroll
      for (int u = 0; u < 4; ++u)
#pragma unroll
        for (int v = 0; v < 4; ++v) acc[u][v] = fmaf(av[u], bvv[v], acc[u][v]);
    }
    __syncthreads();
  }
#pragma unroll
  for (int u = 0; u < 4; ++u)
#pragma unroll
    for (int v = 0; v < 4; ++v)
      atomicAdd(&R[(size_t)(tp * 64 + ty * 4 + u) * DP + tq * 64 + tx * 4 + v], acc[u][v]);
}

// ---------- K11: loss scalars ----------
__global__ __launch_bounds__(256) void k_final(const float* __restrict__ R,
                                               float* __restrict__ out2) {
  int tid = threadIdx.x, bid = blockIdx.x;
  size_t base = (size_t)bid * 1024 + (size_t)tid * 4;
  float4 v = *(const float4*)(R + base);
  int row = (int)(base >> 9);
  int col = (int)(base & 511);
  float tr = 0.f, rg = 0.f;
  float vv[4] = {v.x, v.y, v.z, v.w};
#pragma unroll
  for (int j = 0; j < 4; ++j) {
    int c = col + j;
    if (c == row) tr += vv[j];
    else if (c > row) rg += vv[j] * vv[j];
  }
  tr = wave_reduce_sum(tr);
  rg = wave_reduce_sum(rg);
  __shared__ float sc[8];
  if ((tid & 63) == 0) { sc[tid >> 6] = tr; sc[4 + (tid >> 6)] = rg; }
  __syncthreads();
  if (tid == 0) {
    atomicAdd(&out2[0], -(sc[0] + sc[1] + sc[2] + sc[3]));
    atomicAdd(&out2[1], ALPHAC * (sc[4] + sc[5] + sc[6] + sc[7]));
  }
}

extern "C" void kernel_launch(void* const* d_in, const int* in_sizes, int n_in,
                              void* d_out, int out_size, void* d_ws, size_t ws_size,
                              hipStream_t stream) {
  const float* FF  = (const float*)d_in[0];
  const float* Psi = (const float*)d_in[1];
  const float* CC  = (const float*)d_in[2];
  float* out = (float*)d_out;
  float* ws  = (float*)d_ws;

  float*  psin   = ws + O_PSIN;
  float*  g0     = ws + O_GPSI0;
  float*  g1     = ws + O_GPSI1;
  float*  g2     = ws + O_PSIN;   // reuse: psin dead after k_csum
  float*  g3     = ws + O_FFH;    // reuse: ffh region dead after k_buildA
  ushort* ffh    = (ushort*)(ws + O_FFH);
  ushort* Yh     = (ushort*)(ws + O_YTH);
  float*  rowsum = ws + O_ROWSUM;
  float*  drs    = ws + O_DRS;
  float*  tc     = ws + O_TC;
  int*    cnt    = (int*)(ws + O_CNT);
  int*    order  = (int*)(ws + O_ORDER);
  int*    offs   = (int*)(ws + O_OFFS);
  int*    offsw  = (int*)(ws + O_OFFSW);
  int*    assign = (int*)(ws + O_ASSIGN);
  float*  Rm     = ws + O_R;
  float*  snorm  = ws + O_SNORM;
  ushort* Ah     = (ushort*)(ws + O_AHI);

  hipMemsetAsync(rowsum, 0, (O_SNORM - O_ROWSUM) * sizeof(float), stream);
  hipMemsetAsync(out + OUT_SCAL, 0, 2 * sizeof(float), stream);

  // clustering chain (fp32)
  k_l2norm_ff<<<NPTS, 256, 0, stream>>>(FF, ffh);
  k_l2norm_f32<<<NPTS, 256, 0, stream>>>(Psi, psin, snorm);
  k_cnorm<<<NC, 256, 0, stream>>>(CC, tc);
  k_logitsG<<<256, 256, 0, stream>>>(psin, CC, tc, snorm, out + OUT_LOGITS);
  k_argmax<<<2048, 256, 0, stream>>>(out + OUT_LOGITS, assign, cnt);
  k_prefix<<<1, NC, 0, stream>>>(cnt, offs, offsw);
  k_scatter<<<32, 256, 0, stream>>>(assign, offsw, order);
  k_csum<<<NC, 256, 0, stream>>>(offs, cnt, order, psin, CC, out + OUT_CENTERS);

  // neuralef chain (MFMA)
  k_buildA<<<2080, 256, 0, stream>>>(ffh, Ah, rowsum);
  k_drs<<<32, 256, 0, stream>>>(rowsum, drs);
  k_ytrans<<<dim3(128, 8), 256, 0, stream>>>(Psi, drs, Yh);
  k_gpsiM<<<512, 256, 0, stream>>>(Ah, Yh, g0, g1, g2, g3);
  k_R<<<dim3(64, 8), 256, 0, stream>>>(Psi, g0, g1, g2, g3, drs, Rm);
  k_final<<<256, 256, 0, stream>>>(Rm, out + OUT_SCAL);
}

// Round 8
// 633.606 us; speedup vs baseline: 1.3413x; 1.3413x over previous
//
#include <hip/hip_runtime.h>

// Segmenter forward: clustering (logits/argmax/EMA centers) + neuralef loss.
// Round 8: k_csum (one-block-per-cluster, 241us + pathological imbalance)
// replaced by row-balanced run-accumulate over the cluster-sorted order list
// (256 blocks x 32 rows, register runs, atomic flush per run). k_cfin back.

#define NPTS 8192
#define DM   768
#define DP   512
#define NC   128
#define SCALE 0.001220703125f   // 10/8192, exact
#define ALPHAC 0.02f

// ---- ws offsets in float elements ----
#define O_PSIN   0ul            // 8192*512 fp32 (reused as g2 after clustering)
#define O_GPSI0  4194304ul      // 8192*512 fp32 (kz=0 partial; first 64K = csum early)
#define O_GPSI1  8388608ul      // 8192*512 fp32 (kz=1 partial)
#define O_FFH    12582912ul     // 8192*768 bf16 (region reused as g3 after buildA)
#define O_YTH    18874368ul     // 512*8192 bf16 (transposed, scaled)
#define O_ROWSUM 23068672ul     // 8192
#define O_DRS    23076864ul     // 8192
#define O_TC     23085056ul     // 128
#define O_CNT    23085184ul     // 128 (int)
#define O_ORDER  23085312ul     // 8192 (int, cluster-sorted row ids)
#define O_OFFS   23093504ul     // 128 (int)
#define O_OFFSW  23093632ul     // 128 (int)
#define O_ASSIGN 23150848ul     // 8192 int
#define O_R      23159040ul     // 512*512
#define O_SNORM  23421184ul     // 8192
#define O_AHI    23429376ul     // 8192*8192 bf16 (single plane)
#define WS_END   56983808ul     // ~228 MB

// output offsets (floats)
#define OUT_LOGITS  0ul
#define OUT_CENTERS 1048576ul
#define OUT_SCAL    1114112ul

typedef short  short8 __attribute__((ext_vector_type(8)));
typedef float  f32x4  __attribute__((ext_vector_type(4)));

__device__ __forceinline__ float wave_reduce_sum(float v) {
#pragma unroll
  for (int m = 1; m < 64; m <<= 1) v += __shfl_xor(v, m, 64);
  return v;
}

__device__ __forceinline__ unsigned short f2bf(float x) {
  unsigned int u = __float_as_uint(x);
  unsigned int r = (u + 0x7fffu + ((u >> 16) & 1u)) >> 16;  // RNE
  return (unsigned short)r;
}
__device__ __forceinline__ float bf2f(unsigned short b) {
  return __uint_as_float((unsigned int)b << 16);
}

// async global->LDS 16B: HW writes wave-uniform base + lane*16
__device__ __forceinline__ void stage16(ushort* lds_wave_base, ushort* lds_exact,
                                        const ushort* g) {
#if __has_builtin(__builtin_amdgcn_global_load_lds)
  __builtin_amdgcn_global_load_lds(
      (const __attribute__((address_space(1))) unsigned int*)g,
      (__attribute__((address_space(3))) unsigned int*)lds_wave_base, 16, 0, 0);
#else
  *(uint4*)lds_exact = *(const uint4*)g;
#endif
}

// LDS plane layout: [ROWS][32 bf16], chunk slot s of row holds global k-chunk
// s ^ ((row>>1)&3): 16-lane frag reads map to 8 distinct bank-quads (2-way, free)
__device__ __forceinline__ short8 read_frag(const ushort* plane, int row, int x) {
  int kc = x ^ ((row >> 1) & 3);
  return *(const short8*)(plane + row * 32 + kc * 8);
}

// stage one [ROWS][32] plane from global (row0.., k0..k0+32) with pre-swizzled src
template <int ROWS>
__device__ __forceinline__ void stage_plane(ushort* ldsP, const ushort* __restrict__ src,
                                            int stride, int row0, int k0, int tid) {
  constexpr int NIT = ROWS * 4 / 256;
#pragma unroll
  for (int j = 0; j < NIT; ++j) {
    int c = j * 256 + tid;
    int row = c >> 2;
    int kc = (c & 3) ^ ((row >> 1) & 3);
    stage16(ldsP + (size_t)(c & ~63) * 8, ldsP + (size_t)c * 8,
            src + (size_t)(row0 + row) * stride + k0 + kc * 8);
  }
}

// ================= templated MFMA GEMM core (single bf16 plane per side) =====
template <int BM, int BN>
__device__ void gemm_core(const ushort* __restrict__ aH, const ushort* __restrict__ bH,
                          int strideA, int strideB, int rowA0, int rowB0,
                          int kBase, int kLen, ushort* lds, f32x4 (&acc)[4][BN / 32]) {
  constexpr int NF = BN / 32;
  constexpr int OFF_AH = 0;
  constexpr int OFF_BH = BM * 32;

  const int tid = threadIdx.x;
  const int lane = tid & 63;
  const int l15 = lane & 15;
  const int x16 = lane >> 4;
  const int wid = tid >> 6, wr = wid >> 1, wc = wid & 1;
  const int arow = wr * 64;
  const int bcol = wc * (BN / 2);

  for (int ks = 0; ks < kLen; ks += 32) {
    const int k0 = kBase + ks;
    stage_plane<BM>(lds + OFF_AH, aH, strideA, rowA0, k0, tid);
    stage_plane<BN>(lds + OFF_BH, bH, strideB, rowB0, k0, tid);
    __syncthreads();
    short8 ah[4];
#pragma unroll
    for (int m = 0; m < 4; ++m)
      ah[m] = read_frag(lds + OFF_AH, arow + m * 16 + l15, x16);
#pragma unroll
    for (int n = 0; n < NF; ++n) {
      short8 bh = read_frag(lds + OFF_BH, bcol + n * 16 + l15, x16);
#pragma unroll
      for (int m = 0; m < 4; ++m)
        acc[m][n] = __builtin_amdgcn_mfma_f32_16x16x32_bf16(ah[m], bh, acc[m][n], 0, 0, 0);
    }
    __syncthreads();
  }
}

// ---------- K1a: L2 normalize FF rows -> bf16 hi plane ----------
__global__ __launch_bounds__(256) void k_l2norm_ff(const float* __restrict__ in,
                                                   ushort* __restrict__ oh) {
  int row = blockIdx.x;
  const float* r = in + (size_t)row * DM;
  float v[3];
  float ss = 0.f;
#pragma unroll
  for (int s = 0; s < 3; ++s) { v[s] = r[threadIdx.x + s * 256]; ss += v[s] * v[s]; }
  ss = wave_reduce_sum(ss);
  __shared__ float w[4];
  if ((threadIdx.x & 63) == 0) w[threadIdx.x >> 6] = ss;
  __syncthreads();
  float inv = 1.0f / fmaxf(sqrtf(w[0] + w[1] + w[2] + w[3]), 1e-12f);
#pragma unroll
  for (int s = 0; s < 3; ++s)
    oh[(size_t)row * DM + threadIdx.x + s * 256] = f2bf(v[s] * inv);
}

// ---------- K1b: L2 normalize Psi rows -> fp32 (+ snorm = sum(psin^2)) ----------
__global__ __launch_bounds__(256) void k_l2norm_f32(const float* __restrict__ in,
                                                    float* __restrict__ out,
                                                    float* __restrict__ snorm) {
  int row = blockIdx.x;
  const float* r = in + (size_t)row * DP;
  float v[2];
  float ss = 0.f;
#pragma unroll
  for (int s = 0; s < 2; ++s) { v[s] = r[threadIdx.x + s * 256]; ss += v[s] * v[s]; }
  ss = wave_reduce_sum(ss);
  __shared__ float w[4];
  if ((threadIdx.x & 63) == 0) w[threadIdx.x >> 6] = ss;
  __syncthreads();
  float tot = w[0] + w[1] + w[2] + w[3];
  float inv = 1.0f / fmaxf(sqrtf(tot), 1e-12f);
#pragma unroll
  for (int s = 0; s < 2; ++s)
    out[(size_t)row * DP + threadIdx.x + s * 256] = v[s] * inv;
  if (threadIdx.x == 0) snorm[row] = tot * inv * inv;
}

// ---------- K2: cluster-center squared norms ----------
__global__ __launch_bounds__(256) void k_cnorm(const float* __restrict__ cc,
                                               float* __restrict__ tc) {
  int c = blockIdx.x;
  float x0 = cc[(size_t)c * DP + threadIdx.x];
  float x1 = cc[(size_t)c * DP + threadIdx.x + 256];
  float ss = wave_reduce_sum(x0 * x0 + x1 * x1);
  __shared__ float w[4];
  if ((threadIdx.x & 63) == 0) w[threadIdx.x >> 6] = ss;
  __syncthreads();
  if (threadIdx.x == 0) tc[c] = w[0] + w[1] + w[2] + w[3];
}

// ---------- K3a: logits = 2*psin@cc^T - snorm_i - tc_j  (fp32 tile GEMM) ----------
__global__ __launch_bounds__(256) void k_logitsG(const float* __restrict__ psin,
                                                 const float* __restrict__ cc,
                                                 const float* __restrict__ tc,
                                                 const float* __restrict__ snorm,
                                                 float* __restrict__ out_logits) {
  __shared__ float Ps[64][32];    // [k][row]
  __shared__ float Cs[64][128];   // [k][col]
  const int r0 = blockIdx.x * 32;
  const int tid = threadIdx.x;
  const int tx = tid & 31, ty = tid >> 5;   // cols tx*4.., rows ty*4..
  float acc[4][4] = {};

  for (int k0 = 0; k0 < DP; k0 += 64) {
#pragma unroll
    for (int j = 0; j < 2; ++j) {
      int idx = tid * 2 + j;
      int row = idx >> 4, q = idx & 15;
      float4 v = *(const float4*)(psin + (size_t)(r0 + row) * DP + k0 + q * 4);
      Ps[q * 4 + 0][row] = v.x; Ps[q * 4 + 1][row] = v.y;
      Ps[q * 4 + 2][row] = v.z; Ps[q * 4 + 3][row] = v.w;
    }
#pragma unroll
    for (int j = 0; j < 8; ++j) {
      int idx = tid * 8 + j;
      int c = idx >> 4, q = idx & 15;
      float4 v = *(const float4*)(cc + (size_t)c * DP + k0 + q * 4);
      Cs[q * 4 + 0][c] = v.x; Cs[q * 4 + 1][c] = v.y;
      Cs[q * 4 + 2][c] = v.z; Cs[q * 4 + 3][c] = v.w;
    }
    __syncthreads();
#pragma unroll 8
    for (int k = 0; k < 64; ++k) {
      float a4[4], b4[4];
      *(float4*)a4 = *(const float4*)&Ps[k][ty * 4];
      *(float4*)b4 = *(const float4*)&Cs[k][tx * 4];
#pragma unroll
      for (int u = 0; u < 4; ++u)
#pragma unroll
        for (int v = 0; v < 4; ++v) acc[u][v] = fmaf(a4[u], b4[v], acc[u][v]);
    }
    __syncthreads();
  }

  float4 tcv = *(const float4*)(tc + tx * 4);
#pragma unroll
  for (int u = 0; u < 4; ++u) {
    int row = r0 + ty * 4 + u;
    float sn = snorm[row];
    float4 o;
    o.x = 2.0f * acc[u][0] - sn - tcv.x;
    o.y = 2.0f * acc[u][1] - sn - tcv.y;
    o.z = 2.0f * acc[u][2] - sn - tcv.z;
    o.w = 2.0f * acc[u][3] - sn - tcv.w;
    *(float4*)(out_logits + (size_t)row * NC + tx * 4) = o;
  }
}

// ---------- K3b: argmax per row + cluster counts ----------
__global__ __launch_bounds__(256) void k_argmax(const float* __restrict__ logits,
                                                int* __restrict__ assign,
                                                int* __restrict__ cnt) {
  int row = blockIdx.x * 4 + (threadIdx.x >> 6);
  int lane = threadIdx.x & 63;
  const float* lr = logits + (size_t)row * NC;
  float v0 = lr[lane], v1 = lr[lane + 64];
  float bv; int bi;
  if (v1 > v0) { bv = v1; bi = lane + 64; } else { bv = v0; bi = lane; }
#pragma unroll
  for (int m = 1; m < 64; m <<= 1) {
    float ov = __shfl_xor(bv, m);
    int oi = __shfl_xor(bi, m);
    if (ov > bv || (ov == bv && oi < bi)) { bv = ov; bi = oi; }
  }
  if (lane == 0) {
    assign[row] = bi;
    atomicAdd(&cnt[bi], 1);
  }
}

// ---------- K4a: exclusive prefix of cluster counts ----------
__global__ __launch_bounds__(NC) void k_prefix(const int* __restrict__ cnt,
                                               int* __restrict__ offs,
                                               int* __restrict__ offsw) {
  __shared__ int s[NC];
  int t = threadIdx.x;
  int v0 = cnt[t];
  s[t] = v0;
  __syncthreads();
  for (int off = 1; off < NC; off <<= 1) {
    int v = (t >= off) ? s[t - off] : 0;
    __syncthreads();
    s[t] += v;
    __syncthreads();
  }
  int excl = s[t] - v0;
  offs[t] = excl;
  offsw[t] = excl;
}

// ---------- K4b: scatter row ids into cluster-sorted order ----------
__global__ __launch_bounds__(256) void k_scatter(const int* __restrict__ assign,
                                                 int* __restrict__ offsw,
                                                 int* __restrict__ order) {
  int i = blockIdx.x * 256 + threadIdx.x;
  int c = assign[i];
  int pos = atomicAdd(&offsw[c], 1);
  order[pos] = i;
}

// ---------- K4c: row-balanced run accumulation over sorted order ----------
// 256 blocks x 32 rows each; runs of equal cluster accumulate in registers,
// one atomicAdd pair per (run, column). Serial length uniform = 32.
__global__ __launch_bounds__(256) void k_csum2(const int* __restrict__ order,
                                               const int* __restrict__ assign,
                                               const float* __restrict__ psin,
                                               float* __restrict__ csum) {
  int b = blockIdx.x, tid = threadIdx.x;
  __shared__ int sa[32];
  __shared__ int sc[32];
  if (tid < 32) {
    int id = order[b * 32 + tid];
    sa[tid] = id;
    sc[tid] = assign[id];
  }
  __syncthreads();
  float a0 = 0.f, a1 = 0.f;
  int cur = sc[0];
  for (int j = 0; j < 32; ++j) {
    int cj = sc[j];
    if (cj != cur) {
      atomicAdd(&csum[(size_t)cur * DP + tid], a0);
      atomicAdd(&csum[(size_t)cur * DP + tid + 256], a1);
      a0 = 0.f; a1 = 0.f; cur = cj;
    }
    const float* pr = psin + (size_t)sa[j] * DP;
    a0 += pr[tid];
    a1 += pr[tid + 256];
  }
  atomicAdd(&csum[(size_t)cur * DP + tid], a0);
  atomicAdd(&csum[(size_t)cur * DP + tid + 256], a1);
}

// ---------- K5: EMA centers ----------
__global__ __launch_bounds__(256) void k_cfin(const float* __restrict__ cc,
                                              const float* __restrict__ csum,
                                              const int* __restrict__ cnt,
                                              float* __restrict__ out_centers) {
  int idx = blockIdx.x * 256 + threadIdx.x;  // 0..65535
  int c = idx >> 9;
  float denom = fmaxf((float)cnt[c], 1.0f);
  out_centers[idx] = cc[idx] * 0.9f + (csum[idx] / denom) * 0.1f;
}

// ---------- K6: buildA symmetric (upper-tri blocks, mirror via LDS transpose) ----------
__global__ __launch_bounds__(256) void k_buildA(const ushort* __restrict__ ffh,
                                                ushort* __restrict__ Ah,
                                                float* __restrict__ rowsum) {
  __shared__ ushort lds[16384];
  // XCD-bijective swizzle: 2080 = 8 * 260 exact
  int sid = (blockIdx.x & 7) * 260 + (blockIdx.x >> 3);
  int rem = sid;
  int bi = 0;
  while (rem >= 64 - bi) { rem -= 64 - bi; ++bi; }
  int bj = bi + rem;

  f32x4 acc[4][4];
#pragma unroll
  for (int m = 0; m < 4; ++m)
#pragma unroll
    for (int n = 0; n < 4; ++n) acc[m][n] = (f32x4)0.0f;

  gemm_core<128, 128>(ffh, ffh, DM, DM, bi * 128, bj * 128, 0, DM, lds, acc);

  const int tid = threadIdx.x;
  const int lane = tid & 63, l15 = lane & 15;
  const int wid = tid >> 6, wr = wid >> 1, wc = wid & 1;
  const int rbase = bi * 128 + wr * 64;
  const int cbase = bj * 128 + wc * 64;

#pragma unroll
  for (int m = 0; m < 4; ++m) {
#pragma unroll
    for (int r = 0; r < 4; ++r) {
      int grow = rbase + m * 16 + (lane >> 4) * 4 + r;
      float rsv = 0.f;
#pragma unroll
      for (int n = 0; n < 4; ++n) {
        int gcol = cbase + n * 16 + l15;
        float v = fmaxf(acc[m][n][r], 0.f);
        if (grow == gcol) v = 0.f;
        rsv += v;
        Ah[(size_t)grow * NPTS + gcol] = f2bf(v);
      }
      rsv += __shfl_xor(rsv, 1); rsv += __shfl_xor(rsv, 2);
      rsv += __shfl_xor(rsv, 4); rsv += __shfl_xor(rsv, 8);
      if (l15 == 0) atomicAdd(&rowsum[grow], rsv);
    }
  }

  if (bi != bj) {
    __syncthreads();
#pragma unroll
    for (int m = 0; m < 4; ++m) {
#pragma unroll
      for (int n = 0; n < 4; ++n) {
        int lc = wc * 64 + n * 16 + l15;
        int swz = lc & 7;
#pragma unroll
        for (int r = 0; r < 4; ++r) {
          int lr = wr * 64 + m * 16 + (lane >> 4) * 4 + r;
          float v = fmaxf(acc[m][n][r], 0.f);
          lds[lc * 128 + ((((lr >> 3) ^ swz)) << 3) + (lr & 7)] = f2bf(v);
        }
      }
    }
#pragma unroll
    for (int n = 0; n < 4; ++n) {
      float cs = 0.f;
#pragma unroll
      for (int m = 0; m < 4; ++m)
#pragma unroll
        for (int r = 0; r < 4; ++r) cs += fmaxf(acc[m][n][r], 0.f);
      cs += __shfl_xor(cs, 16); cs += __shfl_xor(cs, 32);
      if (lane < 16) atomicAdd(&rowsum[cbase + n * 16 + l15], cs);
    }
    __syncthreads();
    int lc = tid >> 1;
    int cg = (tid & 1) * 8;
    int swz = lc & 7;
    size_t gbase = (size_t)(bj * 128 + lc) * NPTS + bi * 128;
#pragma unroll
    for (int j = 0; j < 8; ++j) {
      int ch = cg + j;
      short8 vv = *(const short8*)&lds[lc * 128 + ((ch ^ swz) << 3)];
      *(short8*)(Ah + gbase + ch * 8) = vv;
    }
  }
}

// ---------- K7: Drs ----------
__global__ __launch_bounds__(256) void k_drs(const float* __restrict__ rowsum,
                                             float* __restrict__ drs) {
  int i = blockIdx.x * 256 + threadIdx.x;
  drs[i] = 1.0f / sqrtf(rowsum[i] * (1.0f / 8191.0f));
}

// ---------- K8: Yt = bf16((SCALE * Drs_k) * Psi)^T  [512][8192] ----------
__global__ __launch_bounds__(256) void k_ytrans(const float* __restrict__ psi,
                                                const float* __restrict__ drs,
                                                ushort* __restrict__ Yh) {
  __shared__ float sm[64][65];
  int k0 = blockIdx.x * 64, d0 = blockIdx.y * 64;
  int tid = threadIdx.x;
  int rr = tid >> 4, c4 = (tid & 15) * 4;
#pragma unroll
  for (int s = 0; s < 4; ++s) {
    int kk = s * 16 + rr;
    float sd = drs[k0 + kk] * SCALE;
    float4 v = *(const float4*)(psi + (size_t)(k0 + kk) * DP + d0 + c4);
    sm[kk][c4 + 0] = v.x * sd; sm[kk][c4 + 1] = v.y * sd;
    sm[kk][c4 + 2] = v.z * sd; sm[kk][c4 + 3] = v.w * sd;
  }
  __syncthreads();
  int d = tid >> 2, kq = (tid & 3) * 16;
  short8 h0, h1;
#pragma unroll
  for (int t = 0; t < 8; ++t) {
    h0[t] = (short)f2bf(sm[kq + t][d]);
    h1[t] = (short)f2bf(sm[kq + 8 + t][d]);
  }
  size_t off = (size_t)(d0 + d) * NPTS + k0 + kq;
  *(short8*)(Yh + off) = h0; *(short8*)(Yh + off + 8) = h1;
}

// ---------- K9: gPsi partial = A_h @ Yt^T (XCD-swizzled 1-D grid of 512) ----------
__global__ __launch_bounds__(256) void k_gpsiM(const ushort* __restrict__ Ah,
                                               const ushort* __restrict__ Yh,
                                               float* __restrict__ g0,
                                               float* __restrict__ g1,
                                               float* __restrict__ g2,
                                               float* __restrict__ g3) {
  __shared__ ushort lds[12288];
  int sw = (blockIdx.x & 7) * 64 + (blockIdx.x >> 3);
  int nb = sw & 1, ib = (sw >> 1) & 63, kz = sw >> 7;
  float* gout = (kz == 0) ? g0 : (kz == 1) ? g1 : (kz == 2) ? g2 : g3;
  f32x4 acc[4][8];
#pragma unroll
  for (int m = 0; m < 4; ++m)
#pragma unroll
    for (int n = 0; n < 8; ++n) acc[m][n] = (f32x4)0.0f;

  gemm_core<128, 256>(Ah, Yh, NPTS, NPTS, ib * 128, nb * 256, kz * 2048, 2048,
                      lds, acc);

  int lane = threadIdx.x & 63, l15 = lane & 15;
  int wid = threadIdx.x >> 6, wr = wid >> 1, wc = wid & 1;
  int rbase = ib * 128 + wr * 64;
  int cbase = nb * 256 + wc * 128;
#pragma unroll
  for (int m = 0; m < 4; ++m) {
#pragma unroll
    for (int r = 0; r < 4; ++r) {
      int grow = rbase + m * 16 + (lane >> 4) * 4 + r;
#pragma unroll
      for (int n = 0; n < 8; ++n) {
        int gcol = cbase + n * 16 + l15;
        gout[(size_t)grow * DP + gcol] = acc[m][n][r];
      }
    }
  }
}

// ---------- K10: R = Psi_l^T @ (Drs_i * (g0+g1+g2+g3)) ----------
__global__ __launch_bounds__(256) void k_R(const float* __restrict__ psi,
                                           const float* __restrict__ g0,
                                           const float* __restrict__ g1,
                                           const float* __restrict__ g2,
                                           const float* __restrict__ g3,
                                           const float* __restrict__ drs,
                                           float* __restrict__ R) {
  int t = blockIdx.x;
  int tp = t & 7, tq = t >> 3;
  int ks = blockIdx.y;
  int tid = threadIdx.x;
  int tx = tid & 15, ty = tid >> 4;
  __shared__ float Ps[32][64];
  __shared__ float Gs[32][64];
  float acc[4][4] = {};

  for (int k0 = ks * 1024; k0 < ks * 1024 + 1024; k0 += 32) {
#pragma unroll
    for (int s = 0; s < 2; ++s) {
      int idx = tid + s * 256;
      int kk = idx >> 4, pq = idx & 15;
      float4 p = *(const float4*)(psi + (size_t)(k0 + kk) * DP + tp * 64 + pq * 4);
      p.x *= SCALE; p.y *= SCALE; p.z *= SCALE; p.w *= SCALE;
      *(float4*)&Ps[kk][pq * 4] = p;
      float dk = drs[k0 + kk];
      size_t goff = (size_t)(k0 + kk) * DP + tq * 64 + pq * 4;
      float4 ga = *(const float4*)(g0 + goff);
      float4 gb = *(const float4*)(g1 + goff);
      float4 gc = *(const float4*)(g2 + goff);
      float4 gd = *(const float4*)(g3 + goff);
      ga.x = (ga.x + gb.x + gc.x + gd.x) * dk;
      ga.y = (ga.y + gb.y + gc.y + gd.y) * dk;
      ga.z = (ga.z + gb.z + gc.z + gd.z) * dk;
      ga.w = (ga.w + gb.w + gc.w + gd.w) * dk;
      *(float4*)&Gs[kk][pq * 4] = ga;
    }
    __syncthreads();
#pragma unroll 8
    for (int k = 0; k < 32; ++k) {
      float av[4], bvv[4];
      *(float4*)&av[0] = *(const float4*)&Ps[k][ty * 4];
      *(float4*)&bvv[0] = *(const float4*)&Gs[k][tx * 4];
#pragma unroll
      for (int u = 0; u < 4; ++u)
#pragma unroll
        for (int v = 0; v < 4; ++v) acc[u][v] = fmaf(av[u], bvv[v], acc[u][v]);
    }
    __syncthreads();
  }
#pragma unroll
  for (int u = 0; u < 4; ++u)
#pragma unroll
    for (int v = 0; v < 4; ++v)
      atomicAdd(&R[(size_t)(tp * 64 + ty * 4 + u) * DP + tq * 64 + tx * 4 + v], acc[u][v]);
}

// ---------- K11: loss scalars ----------
__global__ __launch_bounds__(256) void k_final(const float* __restrict__ R,
                                               float* __restrict__ out2) {
  int tid = threadIdx.x, bid = blockIdx.x;
  size_t base = (size_t)bid * 1024 + (size_t)tid * 4;
  float4 v = *(const float4*)(R + base);
  int row = (int)(base >> 9);
  int col = (int)(base & 511);
  float tr = 0.f, rg = 0.f;
  float vv[4] = {v.x, v.y, v.z, v.w};
#pragma unroll
  for (int j = 0; j < 4; ++j) {
    int c = col + j;
    if (c == row) tr += vv[j];
    else if (c > row) rg += vv[j] * vv[j];
  }
  tr = wave_reduce_sum(tr);
  rg = wave_reduce_sum(rg);
  __shared__ float sc[8];
  if ((tid & 63) == 0) { sc[tid >> 6] = tr; sc[4 + (tid >> 6)] = rg; }
  __syncthreads();
  if (tid == 0) {
    atomicAdd(&out2[0], -(sc[0] + sc[1] + sc[2] + sc[3]));
    atomicAdd(&out2[1], ALPHAC * (sc[4] + sc[5] + sc[6] + sc[7]));
  }
}

extern "C" void kernel_launch(void* const* d_in, const int* in_sizes, int n_in,
                              void* d_out, int out_size, void* d_ws, size_t ws_size,
                              hipStream_t stream) {
  const float* FF  = (const float*)d_in[0];
  const float* Psi = (const float*)d_in[1];
  const float* CC  = (const float*)d_in[2];
  float* out = (float*)d_out;
  float* ws  = (float*)d_ws;

  float*  psin   = ws + O_PSIN;
  float*  g0     = ws + O_GPSI0;
  float*  g1     = ws + O_GPSI1;
  float*  g2     = ws + O_PSIN;   // reuse: psin dead after k_csum2
  float*  g3     = ws + O_FFH;    // reuse: ffh region dead after k_buildA
  float*  csum   = ws + O_GPSI0;  // first 64K of g0 region (dead until k_gpsiM)
  ushort* ffh    = (ushort*)(ws + O_FFH);
  ushort* Yh     = (ushort*)(ws + O_YTH);
  float*  rowsum = ws + O_ROWSUM;
  float*  drs    = ws + O_DRS;
  float*  tc     = ws + O_TC;
  int*    cnt    = (int*)(ws + O_CNT);
  int*    order  = (int*)(ws + O_ORDER);
  int*    offs   = (int*)(ws + O_OFFS);
  int*    offsw  = (int*)(ws + O_OFFSW);
  int*    assign = (int*)(ws + O_ASSIGN);
  float*  Rm     = ws + O_R;
  float*  snorm  = ws + O_SNORM;
  ushort* Ah     = (ushort*)(ws + O_AHI);

  hipMemsetAsync(rowsum, 0, (O_SNORM - O_ROWSUM) * sizeof(float), stream);
  hipMemsetAsync(csum, 0, NC * DP * sizeof(float), stream);
  hipMemsetAsync(out + OUT_SCAL, 0, 2 * sizeof(float), stream);

  // clustering chain (fp32)
  k_l2norm_ff<<<NPTS, 256, 0, stream>>>(FF, ffh);
  k_l2norm_f32<<<NPTS, 256, 0, stream>>>(Psi, psin, snorm);
  k_cnorm<<<NC, 256, 0, stream>>>(CC, tc);
  k_logitsG<<<256, 256, 0, stream>>>(psin, CC, tc, snorm, out + OUT_LOGITS);
  k_argmax<<<2048, 256, 0, stream>>>(out + OUT_LOGITS, assign, cnt);
  k_prefix<<<1, NC, 0, stream>>>(cnt, offs, offsw);
  k_scatter<<<32, 256, 0, stream>>>(assign, offsw, order);
  k_csum2<<<256, 256, 0, stream>>>(order, assign, psin, csum);
  k_cfin<<<256, 256, 0, stream>>>(CC, csum, cnt, out + OUT_CENTERS);

  // neuralef chain (MFMA)
  k_buildA<<<2080, 256, 0, stream>>>(ffh, Ah, rowsum);
  k_drs<<<32, 256, 0, stream>>>(rowsum, drs);
  k_ytrans<<<dim3(128, 8), 256, 0, stream>>>(Psi, drs, Yh);
  k_gpsiM<<<512, 256, 0, stream>>>(Ah, Yh, g0, g1, g2, g3);
  k_R<<<dim3(64, 8), 256, 0, stream>>>(Psi, g0, g1, g2, g3, drs, Rm);
  k_final<<<256, 256, 0, stream>>>(Rm, out + OUT_SCAL);
}